// Round 9
// baseline (546.854 us; speedup 1.0000x reference)
//
#include <hip/hip_runtime.h>
#include <hip/hip_bf16.h>
#include <stdint.h>

#define HEADS 4
#define SLOPE 0.2f

typedef unsigned short u16;
typedef float f32x4 __attribute__((ext_vector_type(4)));
typedef short s16x8 __attribute__((ext_vector_type(8)));
typedef unsigned short u16x4 __attribute__((ext_vector_type(4)));

__device__ __forceinline__ u16 f2bf(float f) {
    unsigned int u = __float_as_uint(f);
    u = (u + 0x7fffu + ((u >> 16) & 1u)) >> 16;   // round-to-nearest-even
    return (u16)u;
}
__device__ __forceinline__ float bf2f(u16 v) {
    return __uint_as_float(((unsigned int)v) << 16);
}
__device__ __forceinline__ float fin(float x) {
    return (x == x && fabsf(x) < 1e30f) ? x : 0.f;
}

// ---------------------------------------------------------------- fused prep
// zero(deg) + cast inp -> Xb (flat [N][128]) + transpose W1/W2/W3.
__global__ void prep_kernel(const float* __restrict__ inp, u16* __restrict__ Xb,
                            const float* __restrict__ W1, u16* __restrict__ Wt1,
                            const float* __restrict__ W2, u16* __restrict__ Wt2,
                            const float* __restrict__ W3, u16* __restrict__ Wt3,
                            int* __restrict__ deg, int N) {
    int i = blockIdx.x * blockDim.x + threadIdx.x;
    int castN = N * 128;
    if (i < N) deg[i] = 0;
    i -= N;
    if (i >= 0 && i < castN) {
        Xb[i] = f2bf(fin(inp[i]));
        return;
    }
    i -= castN;
    if (i >= 0 && i < 128 * 256) {          // W1 [128 x 256] -> Wt1 [256 x 128]
        int k = i >> 8, m = i & 255;
        Wt1[m * 128 + k] = f2bf(fin(W1[i]));
        return;
    }
    i -= 128 * 256;
    if (i >= 0 && i < 256 * 256) {
        int k = i >> 8, m = i & 255;
        Wt2[m * 256 + k] = f2bf(fin(W2[i]));
        return;
    }
    i -= 256 * 256;
    if (i >= 0 && i < 256 * 256) {
        int k = i >> 8, m = i & 255;
        Wt3[m * 256 + k] = f2bf(fin(W3[i]));
    }
}

// ---------------------------------------------------------------- CSR build
__global__ void count_kernel(const int* __restrict__ dst, int* __restrict__ deg,
                             int E, int N) {
    int i = blockIdx.x * blockDim.x + threadIdx.x;
    if (i < E + N) {
        int d = (i < E) ? dst[i] : (i - E);   // self-loops appended
        d = ((unsigned)d < (unsigned)N) ? d : 0;
        atomicAdd(&deg[d], 1);
    }
}

// Single-dispatch scan: block b redundantly sums deg[0 .. b*1024), then scans
// its own 1024-element chunk (O(B^2) pre-sum is cheap at B=49).
__global__ __launch_bounds__(256) void scan_kernel(const int* __restrict__ deg,
                                                   int* __restrict__ rowstart,
                                                   int* __restrict__ cursor, int N) {
    __shared__ int wsum[4];
    __shared__ int sm[256];
    int b = blockIdx.x, tid = threadIdx.x;
    int start = b * 1024;
    int pre = 0;
    for (int i = tid; i < start; i += 256) pre += deg[i];
    #pragma unroll
    for (int off = 1; off <= 32; off <<= 1) pre += __shfl_xor(pre, off);
    if ((tid & 63) == 0) wsum[tid >> 6] = pre;
    __syncthreads();
    int block_pre = wsum[0] + wsum[1] + wsum[2] + wsum[3];

    int base = start + tid * 4;
    int v[4]; int s = 0;
    #pragma unroll
    for (int j = 0; j < 4; j++) { int i = base + j; v[j] = (i < N) ? deg[i] : 0; s += v[j]; }
    sm[tid] = s;
    __syncthreads();
    for (int off = 1; off < 256; off <<= 1) {
        int t = (tid >= off) ? sm[tid - off] : 0;
        __syncthreads();
        sm[tid] += t;
        __syncthreads();
    }
    int run = block_pre + sm[tid] - s;
    #pragma unroll
    for (int j = 0; j < 4; j++) {
        int i = base + j;
        if (i < N) { rowstart[i] = run; cursor[i] = run; run += v[j]; }
    }
    if (b == gridDim.x - 1 && tid == 255) rowstart[N] = block_pre + sm[255];
}

__global__ void scatter_kernel(const int* __restrict__ src, const int* __restrict__ dst,
                               int* __restrict__ cursor, int* __restrict__ csr,
                               int E, int N) {
    int i = blockIdx.x * blockDim.x + threadIdx.x;
    if (i < E + N) {
        int s, d;
        if (i < E) { s = src[i]; d = dst[i]; }
        else       { s = i - E; d = i - E; }
        s = ((unsigned)s < (unsigned)N) ? s : 0;
        d = ((unsigned)d < (unsigned)N) ? d : 0;
        int pos = atomicAdd(&cursor[d], 1);
        if ((unsigned)pos < (unsigned)(E + N)) csr[pos] = s;
    }
}

// ---------------------------------------------------------------- GEMM + fused alphas (v2)
// OPERAND-SWAPPED: A-operand = Wt fragment (channel), B-operand = X fragment (node).
// D[row=channel][col=node]: lane (l16=node, quad) holds 4 CONTIGUOUS channels per
// tile -> u16x4 vectorized stores (16 x 8B vs 64 x 2B scalar in v1), and the alpha
// reduction is 8 values x 2 shuffle steps (quad-reduce, offsets 16/32) vs 128.
// Block tile 64 nodes x 256 ch; wave tile 32 nodes x 128 ch (2 node-tiles x 8 ch-tiles).
__global__ __launch_bounds__(256) void gemm_kernel(
        const u16* __restrict__ X, const u16* __restrict__ Wt,
        u16* __restrict__ Hout, const float* __restrict__ att_src,
        const float* __restrict__ att_dst, float* __restrict__ as_out,
        float* __restrict__ ad_out, int N, int K) {
    int wv = threadIdx.x >> 6, lane = threadIdx.x & 63;
    int quad = lane >> 4, l16 = lane & 15;
    int m0 = (blockIdx.x * 2 + (wv & 1)) * 32;   // node base
    int n0 = (wv >> 1) * 128;                    // channel base

    f32x4 acc[2][8];   // [node-tile r][ch-tile c]
    #pragma unroll
    for (int r = 0; r < 2; r++)
        #pragma unroll
        for (int c = 0; c < 8; c++) acc[r][c] = (f32x4){0.f, 0.f, 0.f, 0.f};

    for (int k0 = 0; k0 < K; k0 += 32) {
        s16x8 xa[2], wb[8];
        #pragma unroll
        for (int r = 0; r < 2; r++) {
            int row = m0 + r * 16 + l16;
            row = row < N ? row : N - 1;
            xa[r] = *(const s16x8*)(X + (size_t)row * K + k0 + quad * 8);
        }
        #pragma unroll
        for (int c = 0; c < 8; c++) {
            int ch = n0 + c * 16 + l16;
            wb[c] = *(const s16x8*)(Wt + (size_t)ch * K + k0 + quad * 8);
        }
        #pragma unroll
        for (int r = 0; r < 2; r++)
            #pragma unroll
            for (int c = 0; c < 8; c++)
                acc[r][c] = __builtin_amdgcn_mfma_f32_16x16x32_bf16(wb[c], xa[r], acc[r][c], 0, 0, 0);
    }

    // att vectors: depend only on (c, quad, j) — load once.
    int head0 = n0 >> 6;
    f32x4 av[8], dv[8];
    #pragma unroll
    for (int c = 0; c < 8; c++) {
        int ch0 = n0 + c * 16 + quad * 4;
        av[c] = *(const f32x4*)(att_src + ch0);
        dv[c] = *(const f32x4*)(att_dst + ch0);
    }

    #pragma unroll
    for (int r = 0; r < 2; r++) {
        int node = m0 + r * 16 + l16;
        float aps[2] = {0.f, 0.f}, apd[2] = {0.f, 0.f};
        #pragma unroll
        for (int c = 0; c < 8; c++) {
            int ch0 = n0 + c * 16 + quad * 4;
            int hh = c >> 2;
            u16x4 ob;
            #pragma unroll
            for (int j = 0; j < 4; j++) {
                float v = acc[r][c][j];
                aps[hh] += v * fin(av[c][j]);
                apd[hh] += v * fin(dv[c][j]);
                ob[j] = f2bf(v);
            }
            if (node < N) *(u16x4*)(Hout + (size_t)node * 256 + ch0) = ob;
        }
        // reduce over the 4 quads (lanes l16, l16+16, l16+32, l16+48)
        #pragma unroll
        for (int off = 16; off <= 32; off <<= 1) {
            aps[0] += __shfl_xor(aps[0], off);
            aps[1] += __shfl_xor(aps[1], off);
            apd[0] += __shfl_xor(apd[0], off);
            apd[1] += __shfl_xor(apd[1], off);
        }
        if (quad == 0 && node < N) {
            as_out[node * 4 + head0]     = aps[0];
            as_out[node * 4 + head0 + 1] = aps[1];
            ad_out[node * 4 + head0]     = apd[0];
            ad_out[node * 4 + head0 + 1] = apd[1];
        }
    }
}

// ---------------------------------------------------------------- fused softmax-gather
// (R6/R8 version — measured 69 us.) Wave per node; 2 half-wave edge slots; lane
// covers 8 channels (16 B load) of head h = (lane&31)>>3. Inline max-free softmax
// (clamp 80). Edge loop unrolled x2 per slot -> 4 independent row loads in flight.
__global__ __launch_bounds__(256) void gather_kernel(
        const u16* __restrict__ Hb, const float* __restrict__ asrc,
        const float* __restrict__ adst, const int* __restrict__ rowstart,
        const int* __restrict__ csr, const float* __restrict__ bias,
        u16* __restrict__ outb, float* __restrict__ outf, int write_f32,
        int N, int Etot) {
    int wv = threadIdx.x >> 6, lane = threadIdx.x & 63;
    int n = blockIdx.x * 4 + wv;
    if (n >= N) return;
    int es = lane >> 5, c = lane & 31;    // edge slot; 8-channel group
    int h = c >> 3;
    int i0 = rowstart[n], i1 = rowstart[n + 1];
    i0 = min(max(i0, 0), Etot);
    i1 = min(max(i1, i0), Etot);

    float adh = adst[n * 4 + h];
    float acc[8];
    float ws = 0.f;
    #pragma unroll
    for (int j = 0; j < 8; j++) acc[j] = 0.f;

    int i = i0 + es;
    for (; i + 2 < i1; i += 4) {
        int sA = csr[i], sB = csr[i + 2];
        sA = ((unsigned)sA < (unsigned)N) ? sA : 0;
        sB = ((unsigned)sB < (unsigned)N) ? sB : 0;
        float eA = asrc[sA * 4 + h] + adh;
        float eB = asrc[sB * 4 + h] + adh;
        s16x8 hvA = *(const s16x8*)(Hb + (size_t)sA * 256 + c * 8);
        s16x8 hvB = *(const s16x8*)(Hb + (size_t)sB * 256 + c * 8);
        eA = eA > 0.f ? eA : SLOPE * eA;
        eB = eB > 0.f ? eB : SLOPE * eB;
        float wA = __expf(fminf(eA, 80.f));
        float wB = __expf(fminf(eB, 80.f));
        ws += wA + wB;
        #pragma unroll
        for (int j = 0; j < 8; j++)
            acc[j] += wA * bf2f((u16)hvA[j]) + wB * bf2f((u16)hvB[j]);
    }
    if (i < i1) {
        int s = csr[i];
        s = ((unsigned)s < (unsigned)N) ? s : 0;
        float e = asrc[s * 4 + h] + adh;
        s16x8 hv = *(const s16x8*)(Hb + (size_t)s * 256 + c * 8);
        e = e > 0.f ? e : SLOPE * e;
        float w = __expf(fminf(e, 80.f));
        ws += w;
        #pragma unroll
        for (int j = 0; j < 8; j++) acc[j] += w * bf2f((u16)hv[j]);
    }

    ws += __shfl_xor(ws, 32);
    #pragma unroll
    for (int j = 0; j < 8; j++) acc[j] += __shfl_xor(acc[j], 32);

    if (es == 0) {
        float invh = (ws > 0.f) ? 1.f / ws : 0.f;
        f32x4 blo = *(const f32x4*)(bias + c * 8);
        f32x4 bhi = *(const f32x4*)(bias + c * 8 + 4);
        size_t base = (size_t)n * 256 + c * 8;
        float o[8];
        #pragma unroll
        for (int j = 0; j < 8; j++) {
            float v = acc[j] * invh + fin(j < 4 ? blo[j] : bhi[j - 4]);
            o[j] = v > 0.f ? v : (__expf(v) - 1.f);   // ELU
        }
        if (write_f32) {
            f32x4 lo = {o[0], o[1], o[2], o[3]}, hi = {o[4], o[5], o[6], o[7]};
            *(f32x4*)(outf + base) = lo;
            *(f32x4*)(outf + base + 4) = hi;
        } else {
            s16x8 ob;
            #pragma unroll
            for (int j = 0; j < 8; j++) ob[j] = (short)f2bf(o[j]);
            *(s16x8*)(outb + base) = ob;
        }
    }
}

// ---------------------------------------------------------------- launch
extern "C" void kernel_launch(void* const* d_in, const int* in_sizes, int n_in,
                              void* d_out, int out_size, void* d_ws, size_t ws_size,
                              hipStream_t stream) {
    const float* inp  = (const float*)d_in[0];
    const int*   ei   = (const int*)d_in[1];
    const float* W1   = (const float*)d_in[2];
    const float* at_s1= (const float*)d_in[3];
    const float* at_d1= (const float*)d_in[4];
    const float* b1   = (const float*)d_in[5];
    const float* W2   = (const float*)d_in[6];
    const float* at_s2= (const float*)d_in[7];
    const float* at_d2= (const float*)d_in[8];
    const float* b2   = (const float*)d_in[9];
    const float* W3   = (const float*)d_in[10];
    const float* at_s3= (const float*)d_in[11];
    const float* at_d3= (const float*)d_in[12];
    const float* b3   = (const float*)d_in[13];

    const int N = in_sizes[0] / 128;   // 50000
    const int E = in_sizes[1] / 2;     // 800000
    const int Etot = E + N;
    const int* esrc = ei;
    const int* edst = ei + E;

    char* p = (char*)d_ws;
    auto alloc = [&](size_t b) -> void* {
        void* q = (void*)p;
        p += (b + 255) & ~(size_t)255;
        return q;
    };
    u16*   Xb       = (u16*)alloc((size_t)N * 256 * 2);
    u16*   Hb       = (u16*)alloc((size_t)N * 256 * 2);
    u16*   Wt1      = (u16*)alloc((size_t)128 * 256 * 2);
    u16*   Wt2      = (u16*)alloc((size_t)256 * 256 * 2);
    u16*   Wt3      = (u16*)alloc((size_t)256 * 256 * 2);
    float* asb      = (float*)alloc((size_t)N * 4 * 4);
    float* adb      = (float*)alloc((size_t)N * 4 * 4);
    int*   deg      = (int*)alloc((size_t)N * 4);
    int*   rowstart = (int*)alloc((size_t)(N + 1) * 4);
    int*   cursor   = (int*)alloc((size_t)N * 4);
    int*   csr      = (int*)alloc((size_t)Etot * 4);
    float* outf     = (float*)d_out;

    const int SB = (N + 1023) / 1024;
    const int prep_total = N + N * 128 + 128 * 256 + 2 * 256 * 256;

    prep_kernel<<<(prep_total + 255) / 256, 256, 0, stream>>>(
        inp, Xb, W1, Wt1, W2, Wt2, W3, Wt3, deg, N);
    count_kernel<<<(Etot + 255) / 256, 256, 0, stream>>>(edst, deg, E, N);
    scan_kernel<<<SB, 256, 0, stream>>>(deg, rowstart, cursor, N);
    scatter_kernel<<<(Etot + 255) / 256, 256, 0, stream>>>(esrc, edst, cursor, csr, E, N);

    const int gemm_grid = (N + 63) / 64;
    const int node_grid = (N + 3) / 4;

    // layer 1 (K=128)
    gemm_kernel<<<gemm_grid, 256, 0, stream>>>(Xb, Wt1, Hb, at_s1, at_d1, asb, adb, N, 128);
    gather_kernel<<<node_grid, 256, 0, stream>>>(Hb, asb, adb, rowstart, csr, b1,
                                                 Xb, outf, 0, N, Etot);
    // layer 2 (K=256)
    gemm_kernel<<<gemm_grid, 256, 0, stream>>>(Xb, Wt2, Hb, at_s2, at_d2, asb, adb, N, 256);
    gather_kernel<<<node_grid, 256, 0, stream>>>(Hb, asb, adb, rowstart, csr, b2,
                                                 Xb, outf, 0, N, Etot);
    // layer 3 (K=256) -> fp32 d_out
    gemm_kernel<<<gemm_grid, 256, 0, stream>>>(Xb, Wt3, Hb, at_s3, at_d3, asb, adb, N, 256);
    gather_kernel<<<node_grid, 256, 0, stream>>>(Hb, asb, adb, rowstart, csr, b3,
                                                 Xb, outf, 1, N, Etot);
}